// Round 8
// baseline (33.862 us; speedup 1.0000x reference)
//
#include <hip/hip_runtime.h>
#include <math.h>

#define NTHREADS 512
#define MAXN 4096
#define PER 8            // keys per thread = MAXN / NTHREADS
#define DETS 100
#define CMAX 256         // max chunk size (mask width)
#define NWAVES (NTHREADS / 64)

static __device__ __forceinline__ float iou_f(float ax1, float ay1, float ax2, float ay2, float aar,
                                              float bx1, float by1, float bx2, float by2, float bar) {
#pragma clang fp contract(off)
    float xx1 = fmaxf(ax1, bx1), yy1 = fmaxf(ay1, by1);
    float xx2 = fminf(ax2, bx2), yy2 = fminf(ay2, by2);
    float iw = fmaxf((xx2 - xx1) + 1.0f, 0.0f);
    float ih = fmaxf((yy2 - yy1) + 1.0f, 0.0f);
    float inter = iw * ih;
    return inter / ((aar + bar) - inter);
}

__global__ __launch_bounds__(NTHREADS) void postproc_kernel(
    const float* __restrict__ logits,   // (B,N,2)
    const float* __restrict__ regr,     // (B,N,8)
    const float* __restrict__ props,    // (B,N,4)
    float* __restrict__ out,            // (B,100,5) ++ (B,100) ++ (B,100)
    int B, int N)
{
#pragma clang fp contract(off)
    const int b    = blockIdx.x;
    const int tid  = threadIdx.x;
    const int lane = tid & 63;
    const int wid  = tid >> 6;

    __shared__ __align__(16) unsigned long long keysel[CMAX];     // 2 KB
    __shared__ unsigned hist4k[4096];                             // 16 KB
    __shared__ unsigned s_super[64];
    __shared__ unsigned long long rowmask[CMAX][4];               // 8 KB suppression rows
    __shared__ unsigned rowNZ[CMAX];
    __shared__ unsigned supk[CMAX];
    __shared__ float bx1s[CMAX], by1s[CMAX], bx2s[CMAX], by2s[CMAX], bars[CMAX], bscs[CMAX]; // 6 KB
    __shared__ float kb[5][DETS + 4];
    __shared__ int s_kept, s_cnt, s_C, s_fb;
    __shared__ unsigned long long s_prefix, s_T;
    __shared__ int s_target, s_done, s_findkey;

    const float* lg = logits + (size_t)b * N * 2;
    const float* rg = regr   + (size_t)b * N * 8;
    const float* pp = props  + (size_t)b * N * 4;

    // ---------------- Phase A: keys in registers (coalesced loads) ----------------
    unsigned long long v[PER];
#pragma unroll
    for (int s = 0; s < PER; ++s) {
        int a = s * NTHREADS + tid;
        unsigned long long key;
        if (a < N) {
            float2 l = ((const float2*)lg)[a];
            // softmax[:,1] bit-exact: one exp arg is exactly 0 -> e=1
            float zmax = fmaxf(l.x, l.y), zmin = fminf(l.x, l.y);
            float e   = (float)exp((double)(zmin - zmax));
            float den = e + 1.0f;
            float sscore = (l.y >= l.x) ? (1.0f / den) : (e / den);
            float f = (sscore > 0.05f) ? sscore : -1e30f;
            unsigned u = __float_as_uint(f);
            u = (u & 0x80000000u) ? ~u : (u | 0x80000000u);     // monotone float->uint
            key = ((unsigned long long)(~u) << 32) | (unsigned)a; // small key = best
        } else key = ~0ull;
        v[s] = key;
    }
    if (tid == 0) s_kept = 0;

    float* obox = out + (size_t)b * DETS * 5;
    float* olab = out + (size_t)B * DETS * 5 + (size_t)b * DETS;
    float* oval = out + (size_t)B * DETS * 5 + (size_t)B * DETS + (size_t)b * DETS;
    const float CLIPV = (float)4.135166556742356;   // log(1000/16)

    int kept = 0;

    while (kept < DETS) {
        // ---- zero hist + counters ----
        for (int i = tid; i < 4096; i += NTHREADS) hist4k[i] = 0u;
        if (tid == 0) { s_cnt = 0; s_C = 0; s_fb = 0; }
        __syncthreads();                                   // B1

        // ---- one-round histogram: digit = (key32>>18) - 0x1000 ----
        // valid keys -> bins [0x1F,0xAC]; invalid/consumed clamp to 4095
#pragma unroll
        for (int s = 0; s < PER; ++s) {
            unsigned hb = (unsigned)(v[s] >> 50) - 0x1000u;
            if (hb > 4094u) hb = 4095u;
            atomicAdd(&hist4k[hb], 1u);
        }
        __syncthreads();                                   // B2

        // ---- super-bin sums (64 x 64) ----
        {
            unsigned p = 0;
            int base8 = tid * 8;
#pragma unroll
            for (int u = 0; u < 8; ++u) p += hist4k[base8 + u];
#pragma unroll
            for (int off = 4; off; off >>= 1) p += __shfl_down(p, off, 8);
            if ((tid & 7) == 0) s_super[tid >> 3] = p;
        }
        __syncthreads();                                   // B3

        // ---- wave0: largest bin-prefix with count <= 256 ----
        if (tid < 64) {
            int l = tid;
            int inv = (int)hist4k[4095];
            int sp = (int)s_super[l] - ((l == 63) ? inv : 0);
            int incl = sp;
#pragma unroll
            for (int off = 1; off < 64; off <<= 1) {
                int y = __shfl_up(incl, off, 64);
                if (l >= off) incl += y;
            }
            int W = __shfl(incl, 63, 64);
            if (W > 0) {
                int tgt2 = W < CMAX ? W : CMAX;
                int excl = incl - sp;
                bool hit = (excl <= tgt2) && (incl > tgt2);
                unsigned long long bm = __ballot(hit);
                if (bm == 0ull) {
                    // take all remaining valid keys
                    if (l == 0) {
                        s_C = W;
                        s_T = ((unsigned long long)0x7FFBFFFFu << 32) | 0xFFFFFFFFull;
                    }
                } else {
                    int E = (int)(__ffsll(bm) - 1);
                    int prevCum = __shfl(excl, E, 64);
                    int c2 = (E == 63 && l == 63) ? 0 : (int)hist4k[E * 64 + l];
                    int incl2 = c2;
#pragma unroll
                    for (int off = 1; off < 64; off <<= 1) {
                        int y = __shfl_up(incl2, off, 64);
                        if (l >= off) incl2 += y;
                    }
                    int cum = prevCum + incl2;
                    unsigned long long okm = __ballot(cum <= tgt2);
                    int q = (int)__popcll(okm);
                    int Cq = (q > 0) ? __shfl(cum, q - 1, 64) : prevCum;
                    if (l == 0) {
                        if (Cq == 0) { s_fb = 1; s_target = tgt2; }
                        else {
                            int bin = E * 64 + q - 1;
                            unsigned k32end = ((0x1000u + (unsigned)bin + 1u) << 18) - 1u;
                            s_T = ((unsigned long long)k32end << 32) | 0xFFFFFFFFull;
                            s_C = Cq;
                        }
                    }
                }
            }
        }
        __syncthreads();                                   // B4
        if (!s_fb && s_C == 0) break;                      // no valid keys left

        if (s_fb) {
            // ---- exact fallback: byte-wise radix-select of target-th smallest ----
            unsigned (*histw)[256] = (unsigned(*)[256])hist4k;
            if (tid == 0) { s_prefix = 0ull; s_done = 0; s_findkey = 0; }
            for (int round = 0; round < 10; ++round) {
                __syncthreads();
                if (s_done) break;
                int sh = 56 - 8 * round;
                if (s_findkey) {
                    unsigned long long want = s_prefix; int shh = sh + 8;
#pragma unroll
                    for (int s = 0; s < PER; ++s)
                        if ((v[s] >> shh) == want) { s_T = v[s]; s_done = 1; }
                    continue;
                }
                for (int i = tid; i < NWAVES * 256; i += NTHREADS) ((unsigned*)histw)[i] = 0u;
                __syncthreads();
                unsigned long long pfx = s_prefix;
#pragma unroll
                for (int s = 0; s < PER; ++s) {
                    unsigned long long k = v[s];
                    bool match = (round == 0) || ((k >> (sh + 8)) == pfx);
                    if (match) atomicAdd(&histw[wid][(unsigned)((k >> sh) & 0xFFull)], 1u);
                }
                __syncthreads();
                if (tid < 64) {
                    int l = tid;
                    unsigned c0 = 0, c1 = 0, c2 = 0, c3 = 0;
#pragma unroll
                    for (int w2 = 0; w2 < NWAVES; ++w2) {
                        c0 += histw[w2][4*l+0]; c1 += histw[w2][4*l+1];
                        c2 += histw[w2][4*l+2]; c3 += histw[w2][4*l+3];
                    }
                    unsigned q0 = c0, q1 = q0 + c1, q2 = q1 + c2, q3 = q2 + c3;
                    int lanesum = (int)q3, incl = lanesum;
#pragma unroll
                    for (int off = 1; off < 64; off <<= 1) {
                        int y = __shfl_up(incl, off, 64);
                        if (l >= off) incl += y;
                    }
                    unsigned excl = (unsigned)(incl - lanesum);
                    unsigned tg = (unsigned)s_target;
                    if ((excl < tg) && (tg <= (unsigned)incl)) {
                        unsigned within = tg - excl;
                        int u_; unsigned below, bc;
                        if      (within <= q0) { u_ = 0; below = excl;      bc = c0; }
                        else if (within <= q1) { u_ = 1; below = excl + q0; bc = c1; }
                        else if (within <= q2) { u_ = 2; below = excl + q1; bc = c2; }
                        else                   { u_ = 3; below = excl + q2; bc = c3; }
                        unsigned long long npfx = (pfx << 8) | (unsigned)(4*l + u_);
                        s_target = (int)(tg - below);
                        if (sh == 0) { s_T = npfx; s_done = 1; }
                        else { s_prefix = npfx; if (bc == 1u) s_findkey = 1; }
                    }
                }
            }
            __syncthreads();
        }
        unsigned long long T = s_T;

        // ---- compact keys <= T (consumed keys ~0 auto-excluded); mark consumed ----
#pragma unroll
        for (int s = 0; s < PER; ++s) {
            unsigned long long k = v[s];
            bool m = (k <= T);
            unsigned long long mask = __ballot(m);
            int basep = 0;
            if (lane == 0 && mask) basep = atomicAdd(&s_cnt, (int)__popcll(mask));
            basep = __shfl(basep, 0, 64);
            if (m) {
                int off = (int)__popcll(mask & ((1ull << lane) - 1ull));
                keysel[basep + off] = k;
                v[s] = ~0ull;
            }
        }
        __syncthreads();                                   // B5
        const int cnt = s_cnt;                             // <= CMAX guaranteed

        // ---- fused rank-sort + decode (tid < cnt); idle threads zero masks ----
        if (tid < cnt) {
            unsigned long long myk = keysel[tid];
            unsigned idx = (unsigned)(myk & 0xFFFFFFFFull);
            // issue gathers first; rank loop hides their latency
            float2 l  = ((const float2*)lg)[idx];
            float4 p  = ((const float4*)pp)[idx];
            float4 rr = *(const float4*)(rg + (size_t)idx * 8 + 4);
            int r = 0;
            const ulonglong2* kp2 = (const ulonglong2*)keysel;
            int half = cnt >> 1;
            for (int j = 0; j < half; ++j) {
                ulonglong2 two = kp2[j];
                r += (two.x < myk) ? 1 : 0;
                r += (two.y < myk) ? 1 : 0;
            }
            if (cnt & 1) r += (keysel[cnt - 1] < myk) ? 1 : 0;
            // decode (ref float32 op order, no FMA)
            float zmax = fmaxf(l.x, l.y), zmin = fminf(l.x, l.y);
            float e = (float)exp((double)(zmin - zmax));
            float den = e + 1.0f;
            float sv = (l.y >= l.x) ? (1.0f / den) : (e / den);
            float w  = (p.z - p.x) + 1.0f;
            float h  = (p.w - p.y) + 1.0f;
            float cx = p.x + 0.5f * w;
            float cy = p.y + 0.5f * h;
            float dx = rr.x / 10.0f;
            float dy = rr.y / 10.0f;
            float dw = fminf(rr.z / 5.0f, CLIPV);
            float dh = fminf(rr.w / 5.0f, CLIPV);
            float pcx = dx * w + cx;
            float pcy = dy * h + cy;
            float ew = (float)exp((double)dw);
            float eh = (float)exp((double)dh);
            float pw = ew * w;
            float ph = eh * h;
            float x1 = pcx - 0.5f * pw;
            float y1 = pcy - 0.5f * ph;
            float x2 = (pcx + 0.5f * pw) - 1.0f;
            float y2 = (pcy + 0.5f * ph) - 1.0f;
            x1 = fminf(fmaxf(x1, 0.0f), 511.0f);
            y1 = fminf(fmaxf(y1, 0.0f), 511.0f);
            x2 = fminf(fmaxf(x2, 0.0f), 511.0f);
            y2 = fminf(fmaxf(y2, 0.0f), 511.0f);
            bx1s[r] = x1; by1s[r] = y1; bx2s[r] = x2; by2s[r] = y2;
            bars[r] = ((x2 - x1) + 1.0f) * ((y2 - y1) + 1.0f);
            bscs[r] = sv;
        } else if (tid >= CMAX) {
            int z = tid - CMAX;          // 256 idle threads zero exactly 256 rows
            rowmask[z][0] = 0ull; rowmask[z][1] = 0ull;
            rowmask[z][2] = 0ull; rowmask[z][3] = 0ull;
            rowNZ[z] = 0u; supk[z] = 0u;
        }
        __syncthreads();                                   // B6

        // ---- build full suppression bitmask (balanced rows) + kept-check ----
        {
            int q = tid >> 2, sub = tid & 3;
            int i = (sub < 2) ? q : (CMAX - 1 - q);
            if (i < cnt) {
                float x1 = bx1s[i], y1 = by1s[i], x2 = bx2s[i], y2 = by2s[i], ar = bars[i];
                unsigned long long acc0 = 0, acc1 = 0, acc2 = 0, acc3 = 0;
                for (int j = i + 1 + (sub & 1); j < cnt; j += 2) {
                    float iou = iou_f(x1, y1, x2, y2, ar,
                                      bx1s[j], by1s[j], bx2s[j], by2s[j], bars[j]);
                    if (iou > 0.5f) {
                        unsigned long long bit = 1ull << (j & 63);
                        int wq = j >> 6;
                        if (wq == 0) acc0 |= bit; else if (wq == 1) acc1 |= bit;
                        else if (wq == 2) acc2 |= bit; else acc3 |= bit;
                    }
                }
                unsigned long long any = acc0 | acc1 | acc2 | acc3;
                if (any) {
                    if (acc0) atomicOr(&rowmask[i][0], acc0);
                    if (acc1) atomicOr(&rowmask[i][1], acc1);
                    if (acc2) atomicOr(&rowmask[i][2], acc2);
                    if (acc3) atomicOr(&rowmask[i][3], acc3);
                    rowNZ[i] = 1u;       // benign same-value race
                }
            }
            // candidate vs prior-round keepers (only refill rounds)
            if (kept > 0) {
                int c = tid & (CMAX - 1), sl = tid >> 8;
                if (c < cnt) {
                    float x1 = bx1s[c], y1 = by1s[c], x2 = bx2s[c], y2 = by2s[c], ar = bars[c];
                    for (int s2 = sl; s2 < kept; s2 += 2) {
                        float iou = iou_f(kb[0][s2], kb[1][s2], kb[2][s2], kb[3][s2], kb[4][s2],
                                          x1, y1, x2, y2, ar);
                        if (iou > 0.5f) { supk[c] = 1u; break; }
                    }
                }
            }
        }
        __syncthreads();                                   // B7

        // ---- wave0: single greedy resolve over all cnt candidates ----
        if (tid < 64) {
            int l = tid;
            unsigned long long alive[4], pend[4];
#pragma unroll
            for (int w = 0; w < 4; ++w) {
                int c = w * 64 + l;
                bool a  = (c < cnt) && (supk[c] == 0u);
                alive[w] = __ballot(a);
                pend[w]  = __ballot(a && (rowNZ[c] != 0u));
            }
            int fin = CMAX;
            for (;;) {
                int w_ = pend[0] ? 0 : pend[1] ? 1 : pend[2] ? 2 : pend[3] ? 3 : -1;
                if (w_ < 0) break;
                int cb = (int)(__ffsll(pend[w_]) - 1);
                int c  = w_ * 64 + cb;
                // early stop: first DETS keepers finalized below c
                int below = 0;
#pragma unroll
                for (int w = 0; w < 4; ++w)
                    if (w < w_) below += (int)__popcll(alive[w]);
                below += (int)__popcll(alive[w_] & ((1ull << cb) - 1ull));
                if (kept + below >= DETS) { fin = c; break; }
                unsigned long long r0 = rowmask[c][0], r1 = rowmask[c][1];
                unsigned long long r2 = rowmask[c][2], r3 = rowmask[c][3];
                alive[0] &= ~r0; alive[1] &= ~r1; alive[2] &= ~r2; alive[3] &= ~r3;
                pend[w_] &= ~(1ull << cb);
                pend[0] &= alive[0]; pend[1] &= alive[1];
                pend[2] &= alive[2]; pend[3] &= alive[3];
            }
            // finalize: keep only indices < fin
            unsigned long long finA[4];
#pragma unroll
            for (int w = 0; w < 4; ++w) {
                int lo = w * 64;
                unsigned long long m;
                if (fin >= lo + 64) m = ~0ull;
                else if (fin <= lo) m = 0ull;
                else m = (1ull << (fin - lo)) - 1ull;
                finA[w] = alive[w] & m;
            }
            int pc0 = (int)__popcll(finA[0]);
            int pc1 = (int)__popcll(finA[1]);
            int pc2 = (int)__popcll(finA[2]);
            int pc3 = (int)__popcll(finA[3]);
            int tot = pc0 + pc1 + pc2 + pc3;
            int pref[4] = {0, pc0, pc0 + pc1, pc0 + pc1 + pc2};
#pragma unroll
            for (int w = 0; w < 4; ++w) {
                int c = w * 64 + l;
                if ((finA[w] >> l) & 1ull) {
                    int rank = kept + pref[w] + (int)__popcll(finA[w] & ((1ull << l) - 1ull));
                    if (rank < DETS) {
                        float* o = obox + rank * 5;
                        float X1 = bx1s[c], Y1 = by1s[c], X2 = bx2s[c], Y2 = by2s[c];
                        o[0] = X1; o[1] = Y1; o[2] = X2; o[3] = Y2; o[4] = bscs[c];
                        olab[rank] = 1.0f;
                        oval[rank] = 1.0f;
                        kb[0][rank] = X1; kb[1][rank] = Y1;
                        kb[2][rank] = X2; kb[3][rank] = Y2;
                        kb[4][rank] = bars[c];
                    }
                }
            }
            if (l == 0) s_kept = kept + tot;
        }
        __syncthreads();                                   // B8
        kept = s_kept;
    }

    // ---------------- zero-fill remaining output rows ----------------
    int start = kept < DETS ? kept : DETS;
    for (int c2 = start + tid; c2 < DETS; c2 += NTHREADS) {
        float* o = obox + c2 * 5;
        o[0] = 0.0f; o[1] = 0.0f; o[2] = 0.0f; o[3] = 0.0f; o[4] = 0.0f;
        olab[c2] = 0.0f;
        oval[c2] = 0.0f;
    }
}

extern "C" void kernel_launch(void* const* d_in, const int* in_sizes, int n_in,
                              void* d_out, int out_size, void* d_ws, size_t ws_size,
                              hipStream_t stream) {
    (void)d_ws; (void)ws_size; (void)n_in;
    const float* logits = (const float*)d_in[0];
    const float* regr   = (const float*)d_in[1];
    const float* props  = (const float*)d_in[2];
    float* out = (float*)d_out;

    int B = out_size / 700;          // (100*5 + 100 + 100) per image
    if (B < 1) B = 1;
    int N = in_sizes[0] / (2 * B);   // logits = B*N*2

    postproc_kernel<<<B, NTHREADS, 0, stream>>>(logits, regr, props, out, B, N);
}

// Round 9
// 20.613 us; speedup vs baseline: 1.6428x; 1.6428x over previous
//
#include <hip/hip_runtime.h>
#include <math.h>

#define NTHREADS 512
#define MAXN 4096
#define PER 8            // keys per thread = MAXN / NTHREADS
#define DETS 100
#define CHUNK 256        // per-round selection target
#define CAP 512          // chunk capacity
#define NWAVES (NTHREADS / 64)

static __device__ __forceinline__ unsigned long long shfl_bc64(unsigned long long x, int src) {
    int lo = __shfl((int)(unsigned)x, src, 64);
    int hi = __shfl((int)(unsigned)(x >> 32), src, 64);
    return ((unsigned long long)(unsigned)hi << 32) | (unsigned)lo;
}

static __device__ __forceinline__ float iou_f(float ax1, float ay1, float ax2, float ay2, float aar,
                                              float bx1, float by1, float bx2, float by2, float bar) {
#pragma clang fp contract(off)
    float xx1 = fmaxf(ax1, bx1), yy1 = fmaxf(ay1, by1);
    float xx2 = fminf(ax2, bx2), yy2 = fminf(ay2, by2);
    float iw = fmaxf((xx2 - xx1) + 1.0f, 0.0f);
    float ih = fmaxf((yy2 - yy1) + 1.0f, 0.0f);
    float inter = iw * ih;
    return inter / ((aar + bar) - inter);
}

// softmax[:,1] score -> monotone sortable key (small key = best); bit-exact to ref
static __device__ __forceinline__ unsigned long long make_key(float lx, float ly, int a) {
#pragma clang fp contract(off)
    float zmax = fmaxf(lx, ly), zmin = fminf(lx, ly);
    float e   = (float)exp((double)(zmin - zmax));
    float den = e + 1.0f;
    float sscore = (ly >= lx) ? (1.0f / den) : (e / den);
    float f = (sscore > 0.05f) ? sscore : -1e30f;
    unsigned u = __float_as_uint(f);
    u = (u & 0x80000000u) ? ~u : (u | 0x80000000u);
    return ((unsigned long long)(~u) << 32) | (unsigned)a;
}

__global__ __launch_bounds__(NTHREADS) void postproc_kernel(
    const float* __restrict__ logits,   // (B,N,2)
    const float* __restrict__ regr,     // (B,N,8)
    const float* __restrict__ props,    // (B,N,4)
    float* __restrict__ out,            // (B,100,5) ++ (B,100) ++ (B,100)
    int B, int N)
{
#pragma clang fp contract(off)
    const int b    = blockIdx.x;
    const int tid  = threadIdx.x;
    const int lane = tid & 63;
    const int wid  = tid >> 6;

    __shared__ __align__(16) unsigned long long keysel[CAP];   // 4 KB (unsorted chunk)
    __shared__ unsigned hist[2048];                            // 8 KB (bins 0..255 used; 2047 junk)
    __shared__ float bx1s[CAP], by1s[CAP], bx2s[CAP], by2s[CAP], bars[CAP], bscs[CAP]; // 12 KB
    __shared__ float kb[5][DETS + 64];
    __shared__ unsigned tmask[64][2];
    __shared__ unsigned supk[64];
    __shared__ int s_kept, s_cnt, s_C, s_fb;
    __shared__ unsigned long long s_prefix, s_T;
    __shared__ int s_target, s_done, s_findkey;

    const float* lg = logits + (size_t)b * N * 2;
    const float* rg = regr   + (size_t)b * N * 8;
    const float* pp = props  + (size_t)b * N * 4;

    // ---------------- Phase A: keys in registers (float4 = 2 anchors/load) ----------------
    unsigned long long v[PER];
    const float4* lg4 = (const float4*)lg;
#pragma unroll
    for (int s = 0; s < PER / 2; ++s) {
        int L = s * NTHREADS + tid;       // float4 index
        int a0 = 2 * L, a1 = 2 * L + 1;
        if (a1 < N) {
            float4 q = lg4[L];
            v[2*s]   = make_key(q.x, q.y, a0);
            v[2*s+1] = make_key(q.z, q.w, a1);
        } else {
            v[2*s]   = (a0 < N) ? make_key(lg[2*a0], lg[2*a0+1], a0) : ~0ull;
            v[2*s+1] = ~0ull;
        }
    }
    if (tid == 0) s_kept = 0;

    float* obox = out + (size_t)b * DETS * 5;
    float* olab = out + (size_t)B * DETS * 5 + (size_t)b * DETS;
    float* oval = out + (size_t)B * DETS * 5 + (size_t)B * DETS + (size_t)b * DETS;
    const float CLIPV = (float)4.135166556742356;   // log(1000/16)

    int kept = 0;

    while (kept < DETS) {
        // ---- zero used hist bins + counters ----
        if (tid < 256) hist[tid] = 0u;
        if (tid == 0) { s_cnt = 0; s_C = 0; s_fb = 0; }
        __syncthreads();                                   // B1

        // ---- one-round histogram: digit = (key32>>18) - 0x1000 ----
        // valid keys (score in (0.05,1]) -> bins [0x1F,0xAC]; others clamp to junk bin 2047
#pragma unroll
        for (int s = 0; s < PER; ++s) {
            unsigned hb = (unsigned)(v[s] >> 50) - 0x1000u;
            if (hb > 2047u) hb = 2047u;
            atomicAdd(&hist[hb], 1u);
        }
        __syncthreads();                                   // B2

        // ---- wave0: single-phase select (4 bins/lane + one 6-step scan) ----
        if (tid < 64) {
            int l = tid;
            unsigned c0 = hist[4*l+0], c1 = hist[4*l+1], c2 = hist[4*l+2], c3 = hist[4*l+3];
            unsigned q0 = c0, q1 = q0 + c1, q2 = q1 + c2, q3 = q2 + c3;
            int lanesum = (int)q3, incl = lanesum;
#pragma unroll
            for (int off = 1; off < 64; off <<= 1) {
                int y = __shfl_up(incl, off, 64);
                if (l >= off) incl += y;
            }
            int excl = incl - lanesum;
            int W = __shfl(incl, 63, 64);
            if (W > 0) {
                int tgt2 = W < CHUNK ? W : CHUNK;
                if (excl < tgt2 && tgt2 <= incl) {      // boundary lane-group
                    int within = tgt2 - excl;
                    int u_; unsigned cq;
                    if      (within <= (int)q0) { u_ = 0; cq = q0; }
                    else if (within <= (int)q1) { u_ = 1; cq = q1; }
                    else if (within <= (int)q2) { u_ = 2; cq = q2; }
                    else                        { u_ = 3; cq = q3; }
                    int C = excl + (int)cq;             // cum through boundary bin
                    if (C > CAP) { s_fb = 1; s_target = tgt2; }
                    else {
                        int bin = 4 * l + u_;
                        unsigned k32end = ((0x1000u + (unsigned)bin + 1u) << 18) - 1u;
                        s_T = ((unsigned long long)k32end << 32) | 0xFFFFFFFFull;
                        s_C = C;
                    }
                }
            }
        }
        __syncthreads();                                   // B3
        if (!s_fb && s_C == 0) break;                      // no valid keys left

        if (s_fb) {
            // ---- exact fallback: byte-wise radix-select of target-th smallest ----
            unsigned (*histw)[256] = (unsigned(*)[256])hist;
            if (tid == 0) { s_prefix = 0ull; s_done = 0; s_findkey = 0; }
            for (int round = 0; round < 10; ++round) {
                __syncthreads();
                if (s_done) break;
                int sh = 56 - 8 * round;
                if (s_findkey) {
                    unsigned long long want = s_prefix; int shh = sh + 8;
#pragma unroll
                    for (int s = 0; s < PER; ++s)
                        if ((v[s] >> shh) == want) { s_T = v[s]; s_done = 1; }
                    continue;
                }
                for (int i = tid; i < NWAVES * 256; i += NTHREADS) ((unsigned*)histw)[i] = 0u;
                __syncthreads();
                unsigned long long pfx = s_prefix;
#pragma unroll
                for (int s = 0; s < PER; ++s) {
                    unsigned long long k = v[s];
                    bool match = (round == 0) || ((k >> (sh + 8)) == pfx);
                    if (match) atomicAdd(&histw[wid][(unsigned)((k >> sh) & 0xFFull)], 1u);
                }
                __syncthreads();
                if (tid < 64) {
                    int l = tid;
                    unsigned c0 = 0, c1 = 0, c2 = 0, c3 = 0;
#pragma unroll
                    for (int w2 = 0; w2 < NWAVES; ++w2) {
                        c0 += histw[w2][4*l+0]; c1 += histw[w2][4*l+1];
                        c2 += histw[w2][4*l+2]; c3 += histw[w2][4*l+3];
                    }
                    unsigned q0 = c0, q1 = q0 + c1, q2 = q1 + c2, q3 = q2 + c3;
                    int lanesum = (int)q3, incl = lanesum;
#pragma unroll
                    for (int off = 1; off < 64; off <<= 1) {
                        int y = __shfl_up(incl, off, 64);
                        if (l >= off) incl += y;
                    }
                    unsigned excl = (unsigned)(incl - lanesum);
                    unsigned tg = (unsigned)s_target;
                    if ((excl < tg) && (tg <= (unsigned)incl)) {
                        unsigned within = tg - excl;
                        int u_; unsigned below, bc;
                        if      (within <= q0) { u_ = 0; below = excl;      bc = c0; }
                        else if (within <= q1) { u_ = 1; below = excl + q0; bc = c1; }
                        else if (within <= q2) { u_ = 2; below = excl + q1; bc = c2; }
                        else                   { u_ = 3; below = excl + q2; bc = c3; }
                        unsigned long long npfx = (pfx << 8) | (unsigned)(4*l + u_);
                        s_target = (int)(tg - below);
                        if (sh == 0) { s_T = npfx; s_done = 1; }
                        else { s_prefix = npfx; if (bc == 1u) s_findkey = 1; }
                    }
                }
            }
            __syncthreads();
        }
        unsigned long long T = s_T;

        // ---- compact keys <= T (consumed keys ~0 auto-excluded); mark consumed ----
#pragma unroll
        for (int s = 0; s < PER; ++s) {
            unsigned long long k = v[s];
            bool m = (k <= T);
            unsigned long long mask = __ballot(m);
            int basep = 0;
            if (lane == 0 && mask) basep = atomicAdd(&s_cnt, (int)__popcll(mask));
            basep = __shfl(basep, 0, 64);
            if (m) {
                int off = (int)__popcll(mask & ((1ull << lane) - 1ull));
                keysel[basep + off] = k;
                v[s] = ~0ull;
            }
        }
        __syncthreads();                                   // B4
        int cnt = s_cnt;

        // ---- fused rank-counting sort + decode (depth-1, gather latency hidden) ----
        if (tid < cnt) {
            unsigned long long myk = keysel[tid];
            unsigned idx = (unsigned)(myk & 0xFFFFFFFFull);
            // issue gathers first; rank loop hides their latency
            float2 l  = ((const float2*)lg)[idx];
            float4 p  = ((const float4*)pp)[idx];
            float4 rr = *(const float4*)(rg + (size_t)idx * 8 + 4);
            int r = 0;
            const ulonglong2* kp2 = (const ulonglong2*)keysel;
            int half = cnt >> 1;
            for (int j = 0; j < half; ++j) {
                ulonglong2 two = kp2[j];
                r += (two.x < myk) ? 1 : 0;
                r += (two.y < myk) ? 1 : 0;
            }
            if (cnt & 1) r += (keysel[cnt - 1] < myk) ? 1 : 0;
            // decode (ref float32 op order, no FMA)
            float zmax = fmaxf(l.x, l.y), zmin = fminf(l.x, l.y);
            float e = (float)exp((double)(zmin - zmax));
            float den = e + 1.0f;
            float sv = (l.y >= l.x) ? (1.0f / den) : (e / den);
            float w  = (p.z - p.x) + 1.0f;
            float h  = (p.w - p.y) + 1.0f;
            float cx = p.x + 0.5f * w;
            float cy = p.y + 0.5f * h;
            float dx = rr.x / 10.0f;
            float dy = rr.y / 10.0f;
            float dw = fminf(rr.z / 5.0f, CLIPV);
            float dh = fminf(rr.w / 5.0f, CLIPV);
            float pcx = dx * w + cx;
            float pcy = dy * h + cy;
            float ew = (float)exp((double)dw);
            float eh = (float)exp((double)dh);
            float pw = ew * w;
            float ph = eh * h;
            float x1 = pcx - 0.5f * pw;
            float y1 = pcy - 0.5f * ph;
            float x2 = (pcx + 0.5f * pw) - 1.0f;
            float y2 = (pcy + 0.5f * ph) - 1.0f;
            x1 = fminf(fmaxf(x1, 0.0f), 511.0f);
            y1 = fminf(fmaxf(y1, 0.0f), 511.0f);
            x2 = fminf(fmaxf(x2, 0.0f), 511.0f);
            y2 = fminf(fmaxf(y2, 0.0f), 511.0f);
            bx1s[r] = x1; by1s[r] = y1; bx2s[r] = x2; by2s[r] = y2;
            bars[r] = ((x2 - x1) + 1.0f) * ((y2 - y1) + 1.0f);
            bscs[r] = sv;
        }
        __syncthreads();                                   // B5

        // ---- tiled greedy NMS over this chunk (sorted order) ----
        for (int i0 = 0; i0 < cnt && kept < DETS; i0 += 64) {
            if (tid < 64) supk[tid] = (i0 + tid < cnt) ? 0u : 1u;
            else if (tid < 192) { int q = tid - 64; tmask[q >> 1][q & 1] = 0u; }
            __syncthreads();

            // candidate vs already-kept (8 slices)
            {
                int cc = tid & 63, sl = tid >> 6;
                if (supk[cc] == 0u) {
                    int gi = i0 + cc;
                    float x1 = bx1s[gi], y1 = by1s[gi], x2 = bx2s[gi], y2 = by2s[gi], ar = bars[gi];
                    for (int s2 = sl; s2 < kept; s2 += 8) {
                        float iou = iou_f(kb[0][s2], kb[1][s2], kb[2][s2], kb[3][s2], kb[4][s2],
                                          x1, y1, x2, y2, ar);
                        if (iou > 0.5f) { supk[cc] = 1u; break; }
                    }
                }
            }
            // intra-tile 64x64 suppression rows
            {
                int i = tid >> 3, jb = (tid & 7) << 3;
                int gi = i0 + i;
                float x1 = bx1s[gi], y1 = by1s[gi], x2 = bx2s[gi], y2 = by2s[gi], ar = bars[gi];
                unsigned byte = 0;
#pragma unroll
                for (int u = 0; u < 8; ++u) {
                    int j = jb + u;
                    if (j > i) {
                        int gj = i0 + j;
                        float iou = iou_f(x1, y1, x2, y2, ar,
                                          bx1s[gj], by1s[gj], bx2s[gj], by2s[gj], bars[gj]);
                        if (iou > 0.5f) byte |= (1u << u);
                    }
                }
                if (byte) atomicOr(&tmask[i][jb >> 5], byte << (jb & 31));
            }
            __syncthreads();

            // wave0: greedy resolve (skip non-suppressors)
            if (tid < 64) {
                int l = tid;
                unsigned long long row = ((unsigned long long)tmask[l][1] << 32) | tmask[l][0];
                int alive0 = supk[l] ? 0 : 1;
                unsigned long long aliveMask = __ballot(alive0);
                unsigned long long pend = __ballot(alive0 && row != 0ull);
                while (pend) {
                    int c = __ffsll(pend) - 1;
                    unsigned long long rc = shfl_bc64(row, c);
                    aliveMask &= ~rc;                // rc only has bits > c
                    pend &= ~(1ull << c);
                    pend &= aliveMask;
                }
                int alive = (int)((aliveMask >> l) & 1ull);
                int rank = kept + (int)__popcll(aliveMask & ((1ull << l) - 1ull));
                int gi = i0 + l;
                if (alive) {
                    if (rank < DETS) {
                        float* o = obox + rank * 5;
                        o[0] = bx1s[gi]; o[1] = by1s[gi]; o[2] = bx2s[gi]; o[3] = by2s[gi];
                        o[4] = bscs[gi];
                        olab[rank] = 1.0f;
                        oval[rank] = 1.0f;
                    }
                    kb[0][rank] = bx1s[gi]; kb[1][rank] = by1s[gi];
                    kb[2][rank] = bx2s[gi]; kb[3][rank] = by2s[gi];
                    kb[4][rank] = bars[gi];
                }
                if (l == 0) s_kept = kept + (int)__popcll(aliveMask);
            }
            __syncthreads();
            kept = s_kept;
        }
    }

    // ---------------- zero-fill remaining output rows ----------------
    int start = kept < DETS ? kept : DETS;
    for (int c2 = start + tid; c2 < DETS; c2 += NTHREADS) {
        float* o = obox + c2 * 5;
        o[0] = 0.0f; o[1] = 0.0f; o[2] = 0.0f; o[3] = 0.0f; o[4] = 0.0f;
        olab[c2] = 0.0f;
        oval[c2] = 0.0f;
    }
}

extern "C" void kernel_launch(void* const* d_in, const int* in_sizes, int n_in,
                              void* d_out, int out_size, void* d_ws, size_t ws_size,
                              hipStream_t stream) {
    (void)d_ws; (void)ws_size; (void)n_in;
    const float* logits = (const float*)d_in[0];
    const float* regr   = (const float*)d_in[1];
    const float* props  = (const float*)d_in[2];
    float* out = (float*)d_out;

    int B = out_size / 700;          // (100*5 + 100 + 100) per image
    if (B < 1) B = 1;
    int N = in_sizes[0] / (2 * B);   // logits = B*N*2

    postproc_kernel<<<B, NTHREADS, 0, stream>>>(logits, regr, props, out, B, N);
}

// Round 10
// 20.549 us; speedup vs baseline: 1.6478x; 1.0031x over previous
//
#include <hip/hip_runtime.h>
#include <math.h>

#define NTHREADS 512
#define MAXN 4096
#define PER 8            // keys per thread = MAXN / NTHREADS
#define DETS 100
#define CHUNK 256        // per-round selection target
#define CAP 512          // chunk capacity
#define NWAVES (NTHREADS / 64)

static __device__ __forceinline__ unsigned long long shfl_bc64(unsigned long long x, int src) {
    int lo = __shfl((int)(unsigned)x, src, 64);
    int hi = __shfl((int)(unsigned)(x >> 32), src, 64);
    return ((unsigned long long)(unsigned)hi << 32) | (unsigned)lo;
}

static __device__ __forceinline__ float iou_f(float ax1, float ay1, float ax2, float ay2, float aar,
                                              float bx1, float by1, float bx2, float by2, float bar) {
#pragma clang fp contract(off)
    float xx1 = fmaxf(ax1, bx1), yy1 = fmaxf(ay1, by1);
    float xx2 = fminf(ax2, bx2), yy2 = fminf(ay2, by2);
    float iw = fmaxf((xx2 - xx1) + 1.0f, 0.0f);
    float ih = fmaxf((yy2 - yy1) + 1.0f, 0.0f);
    float inter = iw * ih;
    return inter / ((aar + bar) - inter);
}

// softmax[:,1] score -> monotone sortable key (small key = best); bit-exact to ref
static __device__ __forceinline__ unsigned long long make_key(float lx, float ly, int a) {
#pragma clang fp contract(off)
    float zmax = fmaxf(lx, ly), zmin = fminf(lx, ly);
    float e   = (float)exp((double)(zmin - zmax));
    float den = e + 1.0f;
    float sscore = (ly >= lx) ? (1.0f / den) : (e / den);
    float f = (sscore > 0.05f) ? sscore : -1e30f;
    unsigned u = __float_as_uint(f);
    u = (u & 0x80000000u) ? ~u : (u | 0x80000000u);
    return ((unsigned long long)(~u) << 32) | (unsigned)a;
}

__global__ __launch_bounds__(NTHREADS) void postproc_kernel(
    const float* __restrict__ logits,   // (B,N,2)
    const float* __restrict__ regr,     // (B,N,8)
    const float* __restrict__ props,    // (B,N,4)
    float* __restrict__ out,            // (B,100,5) ++ (B,100) ++ (B,100)
    int B, int N)
{
#pragma clang fp contract(off)
    const int b    = blockIdx.x;
    const int tid  = threadIdx.x;
    const int lane = tid & 63;
    const int wid  = tid >> 6;

    __shared__ __align__(16) unsigned long long keysel[CAP];   // 4 KB (unsorted chunk)
    __shared__ unsigned hist[2048];                            // 8 KB (bins 0..255 used; 2047 junk)
    __shared__ float bx1s[CAP], by1s[CAP], bx2s[CAP], by2s[CAP], bars[CAP], bscs[CAP]; // 12 KB
    __shared__ float kb[5][DETS + 64];
    __shared__ unsigned tmask[2][64][2];                       // double-buffered tile rows
    __shared__ unsigned supk[2][64];                           // double-buffered sup flags
    __shared__ int s_kept, s_cnt, s_C, s_fb;
    __shared__ unsigned long long s_prefix, s_T;
    __shared__ int s_target, s_done, s_findkey;

    const float* lg = logits + (size_t)b * N * 2;
    const float* rg = regr   + (size_t)b * N * 8;
    const float* pp = props  + (size_t)b * N * 4;

    // ---------------- Phase A: keys in registers (float4 = 2 anchors/load) ----------------
    unsigned long long v[PER];
    const float4* lg4 = (const float4*)lg;
#pragma unroll
    for (int s = 0; s < PER / 2; ++s) {
        int L = s * NTHREADS + tid;       // float4 index
        int a0 = 2 * L, a1 = 2 * L + 1;
        if (a1 < N) {
            float4 q = lg4[L];
            v[2*s]   = make_key(q.x, q.y, a0);
            v[2*s+1] = make_key(q.z, q.w, a1);
        } else {
            v[2*s]   = (a0 < N) ? make_key(lg[2*a0], lg[2*a0+1], a0) : ~0ull;
            v[2*s+1] = ~0ull;
        }
    }
    if (tid == 0) s_kept = 0;

    float* obox = out + (size_t)b * DETS * 5;
    float* olab = out + (size_t)B * DETS * 5 + (size_t)b * DETS;
    float* oval = out + (size_t)B * DETS * 5 + (size_t)B * DETS + (size_t)b * DETS;
    const float CLIPV = (float)4.135166556742356;   // log(1000/16)

    int kept = 0;

    while (kept < DETS) {
        // ---- zero used hist bins + counters ----
        if (tid < 256) hist[tid] = 0u;
        if (tid == 0) { s_cnt = 0; s_C = 0; s_fb = 0; }
        __syncthreads();                                   // B1

        // ---- one-round histogram: digit = (key32>>18) - 0x1000 ----
        // valid keys (score in (0.05,1]) -> bins [0x1F,0xAC]; others clamp to junk bin 2047
#pragma unroll
        for (int s = 0; s < PER; ++s) {
            unsigned hb = (unsigned)(v[s] >> 50) - 0x1000u;
            if (hb > 2047u) hb = 2047u;
            atomicAdd(&hist[hb], 1u);
        }
        __syncthreads();                                   // B2

        // ---- wave0: single-phase select (4 bins/lane + one 6-step scan) ----
        if (tid < 64) {
            int l = tid;
            unsigned c0 = hist[4*l+0], c1 = hist[4*l+1], c2 = hist[4*l+2], c3 = hist[4*l+3];
            unsigned q0 = c0, q1 = q0 + c1, q2 = q1 + c2, q3 = q2 + c3;
            int lanesum = (int)q3, incl = lanesum;
#pragma unroll
            for (int off = 1; off < 64; off <<= 1) {
                int y = __shfl_up(incl, off, 64);
                if (l >= off) incl += y;
            }
            int excl = incl - lanesum;
            int W = __shfl(incl, 63, 64);
            if (W > 0) {
                int tgt2 = W < CHUNK ? W : CHUNK;
                if (excl < tgt2 && tgt2 <= incl) {      // boundary lane-group
                    int within = tgt2 - excl;
                    int u_; unsigned cq;
                    if      (within <= (int)q0) { u_ = 0; cq = q0; }
                    else if (within <= (int)q1) { u_ = 1; cq = q1; }
                    else if (within <= (int)q2) { u_ = 2; cq = q2; }
                    else                        { u_ = 3; cq = q3; }
                    int C = excl + (int)cq;             // cum through boundary bin
                    if (C > CAP) { s_fb = 1; s_target = tgt2; }
                    else {
                        int bin = 4 * l + u_;
                        unsigned k32end = ((0x1000u + (unsigned)bin + 1u) << 18) - 1u;
                        s_T = ((unsigned long long)k32end << 32) | 0xFFFFFFFFull;
                        s_C = C;
                    }
                }
            }
        }
        __syncthreads();                                   // B3
        if (!s_fb && s_C == 0) break;                      // no valid keys left

        if (s_fb) {
            // ---- exact fallback: byte-wise radix-select of target-th smallest ----
            unsigned (*histw)[256] = (unsigned(*)[256])hist;
            if (tid == 0) { s_prefix = 0ull; s_done = 0; s_findkey = 0; }
            for (int round = 0; round < 10; ++round) {
                __syncthreads();
                if (s_done) break;
                int sh = 56 - 8 * round;
                if (s_findkey) {
                    unsigned long long want = s_prefix; int shh = sh + 8;
#pragma unroll
                    for (int s = 0; s < PER; ++s)
                        if ((v[s] >> shh) == want) { s_T = v[s]; s_done = 1; }
                    continue;
                }
                for (int i = tid; i < NWAVES * 256; i += NTHREADS) ((unsigned*)histw)[i] = 0u;
                __syncthreads();
                unsigned long long pfx = s_prefix;
#pragma unroll
                for (int s = 0; s < PER; ++s) {
                    unsigned long long k = v[s];
                    bool match = (round == 0) || ((k >> (sh + 8)) == pfx);
                    if (match) atomicAdd(&histw[wid][(unsigned)((k >> sh) & 0xFFull)], 1u);
                }
                __syncthreads();
                if (tid < 64) {
                    int l = tid;
                    unsigned c0 = 0, c1 = 0, c2 = 0, c3 = 0;
#pragma unroll
                    for (int w2 = 0; w2 < NWAVES; ++w2) {
                        c0 += histw[w2][4*l+0]; c1 += histw[w2][4*l+1];
                        c2 += histw[w2][4*l+2]; c3 += histw[w2][4*l+3];
                    }
                    unsigned q0 = c0, q1 = q0 + c1, q2 = q1 + c2, q3 = q2 + c3;
                    int lanesum = (int)q3, incl = lanesum;
#pragma unroll
                    for (int off = 1; off < 64; off <<= 1) {
                        int y = __shfl_up(incl, off, 64);
                        if (l >= off) incl += y;
                    }
                    unsigned excl = (unsigned)(incl - lanesum);
                    unsigned tg = (unsigned)s_target;
                    if ((excl < tg) && (tg <= (unsigned)incl)) {
                        unsigned within = tg - excl;
                        int u_; unsigned below, bc;
                        if      (within <= q0) { u_ = 0; below = excl;      bc = c0; }
                        else if (within <= q1) { u_ = 1; below = excl + q0; bc = c1; }
                        else if (within <= q2) { u_ = 2; below = excl + q1; bc = c2; }
                        else                   { u_ = 3; below = excl + q2; bc = c3; }
                        unsigned long long npfx = (pfx << 8) | (unsigned)(4*l + u_);
                        s_target = (int)(tg - below);
                        if (sh == 0) { s_T = npfx; s_done = 1; }
                        else { s_prefix = npfx; if (bc == 1u) s_findkey = 1; }
                    }
                }
            }
            __syncthreads();
        }
        unsigned long long T = s_T;

        // ---- compact keys <= T (consumed keys ~0 auto-excluded); mark consumed ----
#pragma unroll
        for (int s = 0; s < PER; ++s) {
            unsigned long long k = v[s];
            bool m = (k <= T);
            unsigned long long mask = __ballot(m);
            int basep = 0;
            if (lane == 0 && mask) basep = atomicAdd(&s_cnt, (int)__popcll(mask));
            basep = __shfl(basep, 0, 64);
            if (m) {
                int off = (int)__popcll(mask & ((1ull << lane) - 1ull));
                keysel[basep + off] = k;
                v[s] = ~0ull;
            }
        }
        __syncthreads();                                   // B4
        int cnt = s_cnt;

        // ---- fused rank-counting sort + decode (depth-1, gather latency hidden) ----
        if (tid < cnt) {
            unsigned long long myk = keysel[tid];
            unsigned idx = (unsigned)(myk & 0xFFFFFFFFull);
            // issue gathers first; rank loop hides their latency
            float2 l  = ((const float2*)lg)[idx];
            float4 p  = ((const float4*)pp)[idx];
            float4 rr = *(const float4*)(rg + (size_t)idx * 8 + 4);
            int r = 0;
            const ulonglong2* kp2 = (const ulonglong2*)keysel;
            int half = cnt >> 1;
            for (int j = 0; j < half; ++j) {
                ulonglong2 two = kp2[j];
                r += (two.x < myk) ? 1 : 0;
                r += (two.y < myk) ? 1 : 0;
            }
            if (cnt & 1) r += (keysel[cnt - 1] < myk) ? 1 : 0;
            // decode (ref float32 op order, no FMA)
            float zmax = fmaxf(l.x, l.y), zmin = fminf(l.x, l.y);
            float e = (float)exp((double)(zmin - zmax));
            float den = e + 1.0f;
            float sv = (l.y >= l.x) ? (1.0f / den) : (e / den);
            float w  = (p.z - p.x) + 1.0f;
            float h  = (p.w - p.y) + 1.0f;
            float cx = p.x + 0.5f * w;
            float cy = p.y + 0.5f * h;
            float dx = rr.x / 10.0f;
            float dy = rr.y / 10.0f;
            float dw = fminf(rr.z / 5.0f, CLIPV);
            float dh = fminf(rr.w / 5.0f, CLIPV);
            float pcx = dx * w + cx;
            float pcy = dy * h + cy;
            float ew = (float)exp((double)dw);
            float eh = (float)exp((double)dh);
            float pw = ew * w;
            float ph = eh * h;
            float x1 = pcx - 0.5f * pw;
            float y1 = pcy - 0.5f * ph;
            float x2 = (pcx + 0.5f * pw) - 1.0f;
            float y2 = (pcy + 0.5f * ph) - 1.0f;
            x1 = fminf(fmaxf(x1, 0.0f), 511.0f);
            y1 = fminf(fmaxf(y1, 0.0f), 511.0f);
            x2 = fminf(fmaxf(x2, 0.0f), 511.0f);
            y2 = fminf(fmaxf(y2, 0.0f), 511.0f);
            bx1s[r] = x1; by1s[r] = y1; bx2s[r] = x2; by2s[r] = y2;
            bars[r] = ((x2 - x1) + 1.0f) * ((y2 - y1) + 1.0f);
            bscs[r] = sv;
        }
        // init tile-0 masks (parity 0) in the same phase (no extra barrier)
        if (tid < 64) supk[0][tid] = (tid < cnt) ? 0u : 1u;
        else if (tid < 192) { int q = tid - 64; tmask[0][q >> 1][q & 1] = 0u; }
        __syncthreads();                                   // B5

        // ---- tiled greedy NMS over this chunk (sorted order) ----
        for (int i0 = 0; i0 < cnt && kept < DETS; i0 += 64) {
            const int p = (i0 >> 6) & 1;
            // build phase: candidate vs already-kept (8 slices)
            {
                int cc = tid & 63, sl = tid >> 6;
                if (supk[p][cc] == 0u) {
                    int gi = i0 + cc;
                    float x1 = bx1s[gi], y1 = by1s[gi], x2 = bx2s[gi], y2 = by2s[gi], ar = bars[gi];
                    for (int s2 = sl; s2 < kept; s2 += 8) {
                        float iou = iou_f(kb[0][s2], kb[1][s2], kb[2][s2], kb[3][s2], kb[4][s2],
                                          x1, y1, x2, y2, ar);
                        if (iou > 0.5f) { supk[p][cc] = 1u; break; }
                    }
                }
            }
            // intra-tile 64x64 suppression rows
            {
                int i = tid >> 3, jb = (tid & 7) << 3;
                int gi = i0 + i;
                float x1 = bx1s[gi], y1 = by1s[gi], x2 = bx2s[gi], y2 = by2s[gi], ar = bars[gi];
                unsigned byte = 0;
#pragma unroll
                for (int u = 0; u < 8; ++u) {
                    int j = jb + u;
                    if (j > i) {
                        int gj = i0 + j;
                        float iou = iou_f(x1, y1, x2, y2, ar,
                                          bx1s[gj], by1s[gj], bx2s[gj], by2s[gj], bars[gj]);
                        if (iou > 0.5f) byte |= (1u << u);
                    }
                }
                if (byte) atomicOr(&tmask[p][i][jb >> 5], byte << (jb & 31));
            }
            __syncthreads();                               // B6 (build done)

            // resolve phase: wave0 resolves tile p; waves 1-3 init tile p^1 masks
            if (tid < 64) {
                int l = tid;
                unsigned long long row = ((unsigned long long)tmask[p][l][1] << 32) | tmask[p][l][0];
                int alive0 = supk[p][l] ? 0 : 1;
                unsigned long long aliveMask = __ballot(alive0);
                unsigned long long pend = __ballot(alive0 && row != 0ull);
                while (pend) {
                    int c = __ffsll(pend) - 1;
                    unsigned long long rc = shfl_bc64(row, c);
                    aliveMask &= ~rc;                // rc only has bits > c
                    pend &= ~(1ull << c);
                    pend &= aliveMask;
                }
                int alive = (int)((aliveMask >> l) & 1ull);
                int rank = kept + (int)__popcll(aliveMask & ((1ull << l) - 1ull));
                int gi = i0 + l;
                if (alive) {
                    if (rank < DETS) {
                        float* o = obox + rank * 5;
                        o[0] = bx1s[gi]; o[1] = by1s[gi]; o[2] = bx2s[gi]; o[3] = by2s[gi];
                        o[4] = bscs[gi];
                        olab[rank] = 1.0f;
                        oval[rank] = 1.0f;
                    }
                    kb[0][rank] = bx1s[gi]; kb[1][rank] = by1s[gi];
                    kb[2][rank] = bx2s[gi]; kb[3][rank] = by2s[gi];
                    kb[4][rank] = bars[gi];
                }
                if (l == 0) s_kept = kept + (int)__popcll(aliveMask);
            } else if (tid < 128) {
                int z = tid - 64;
                supk[p ^ 1][z] = (i0 + 64 + z < cnt) ? 0u : 1u;
            } else if (tid < 256) {
                int q = tid - 128;
                tmask[p ^ 1][q >> 1][q & 1] = 0u;
            }
            __syncthreads();                               // B7 (resolve + next masks done)
            kept = s_kept;
        }
    }

    // ---------------- zero-fill remaining output rows ----------------
    int start = kept < DETS ? kept : DETS;
    for (int c2 = start + tid; c2 < DETS; c2 += NTHREADS) {
        float* o = obox + c2 * 5;
        o[0] = 0.0f; o[1] = 0.0f; o[2] = 0.0f; o[3] = 0.0f; o[4] = 0.0f;
        olab[c2] = 0.0f;
        oval[c2] = 0.0f;
    }
}

extern "C" void kernel_launch(void* const* d_in, const int* in_sizes, int n_in,
                              void* d_out, int out_size, void* d_ws, size_t ws_size,
                              hipStream_t stream) {
    (void)d_ws; (void)ws_size; (void)n_in;
    const float* logits = (const float*)d_in[0];
    const float* regr   = (const float*)d_in[1];
    const float* props  = (const float*)d_in[2];
    float* out = (float*)d_out;

    int B = out_size / 700;          // (100*5 + 100 + 100) per image
    if (B < 1) B = 1;
    int N = in_sizes[0] / (2 * B);   // logits = B*N*2

    postproc_kernel<<<B, NTHREADS, 0, stream>>>(logits, regr, props, out, B, N);
}